// Round 9
// baseline (1007.499 us; speedup 1.0000x reference)
//
#include <hip/hip_runtime.h>

#define NHEAD 8
#define NT 512
#define KT 32
#define NTILE 32
#define RS 138          // dwords per m-row in kv tile: 8 heads x 17 + 2 pad
#define HS 17           // per-head stride in dwords (16 data + 1 pad, odd -> bank spread)
#define OFF_H 1048576
#define OFF_A 34603008

typedef __fp16 h2 __attribute__((ext_vector_type(2)));
typedef __fp16 h4 __attribute__((ext_vector_type(4)));
typedef __fp16 h8 __attribute__((ext_vector_type(8)));

__device__ __forceinline__ float dot2f(h2 a, h2 b, float c){
#if __has_builtin(__builtin_amdgcn_fdot2)
  return __builtin_amdgcn_fdot2(a, b, c, false);
#else
  return fmaf((float)a[0], (float)b[0], fmaf((float)a[1], (float)b[1], c));
#endif
}

__device__ __forceinline__ void stage_issue(const float* __restrict__ QKV, size_t qkvbase,
                                            int tile, int off, int srow, int shs, int sjp,
                                            float4 sf[4]){
  const float* src = QKV + qkvbase + (size_t)(tile*KT + srow)*768 + off + sjp*32 + shs*4;
  #pragma unroll
  for (int dd = 0; dd < 4; dd++) sf[dd] = *(const float4*)(src + dd*8);
}

__device__ __forceinline__ void stage_write(h2* kvb, int slot, int srow, int shs, int sjp,
                                            const float4 sf[4]){
  #pragma unroll
  for (int hh = 0; hh < 4; hh++){
    h2 lo = __builtin_amdgcn_cvt_pkrtz(((const float*)&sf[0])[hh], ((const float*)&sf[1])[hh]);
    h2 hi = __builtin_amdgcn_cvt_pkrtz(((const float*)&sf[2])[hh], ((const float*)&sf[3])[hh]);
    h4 pk; pk[0]=lo[0]; pk[1]=lo[1]; pk[2]=hi[0]; pk[3]=hi[1];
    *(h4*)&kvb[(slot*KT + srow)*RS + (4*shs+hh)*HS + 2*sjp] = pk;
  }
}

__global__ __launch_bounds__(NT, 6) void egt_fused(
    const float* __restrict__ QKV, const float* __restrict__ E,
    const float* __restrict__ G, float* __restrict__ out)
{
  __shared__ __align__(16) h2 kvb[2*KT*RS];     // K/V ring, 2 slots (35.3 KB)
  __shared__ __align__(16) h4 at2h[2][KT][9];   // A fragments fp16, dbuf (4.6 KB)
  __shared__ float red[8][2][NHEAD][2];
  __shared__ float fin[4][NHEAD];

  const int t   = threadIdx.x;
  const int h   = t & 7;
  const int lh  = (t >> 3) & 1;
  const int mg2 = t >> 4;          // 0..31  (mapping-1: scores/E/G/A io)
  const int w   = t >> 6;
  const int srow = t >> 4;         // staging decode
  const int shs  = (t >> 3) & 1;
  const int sjp  = t & 7;
  const int pmq = t & 7;           // PV decode
  const int pdq = (t >> 3) & 7;
  const int ph  = t >> 6;
  const int b  = blockIdx.x >> 8;
  const int l0 = (blockIdx.x & 255) << 2;
  const size_t qkvbase = (size_t)(b * 1024) * 768;

  const int ebase0 = (b*1024 + l0 + 2*lh) * 8192;
  const int ebase1 = ebase0 + 8192;
  const int eoff = mg2*8 + h;

  // ---- pack Q into registers (fp16 pairs over d) ----
  h2 q0[16], q1[16];
  {
    const float* qp0 = QKV + qkvbase + (size_t)(l0 + 2*lh) * 768 + h;
    const float* qp1 = qp0 + 768;
    #pragma unroll
    for (int jd = 0; jd < 16; jd++){
      q0[jd] = __builtin_amdgcn_cvt_pkrtz(qp0[jd*16], qp0[jd*16 + 8]);
      q1[jd] = __builtin_amdgcn_cvt_pkrtz(qp1[jd*16], qp1[jd*16 + 8]);
    }
  }

  float4 sf[2][4];
  float  e2[2][2];

  // ---- phase-1 prologue: K(0),K(1) + E(0),E(1) in flight ----
  stage_issue(QKV, qkvbase, 0, 256, srow, shs, sjp, sf[0]);
  stage_issue(QKV, qkvbase, 1, 256, srow, shs, sjp, sf[1]);
  e2[0][0] = E[ebase0 + eoff];
  e2[0][1] = E[ebase1 + eoff];
  e2[1][0] = E[ebase0 + 256 + eoff];
  e2[1][1] = E[ebase1 + 256 + eoff];
  stage_write(kvb, 0, srow, shs, sjp, sf[0]);
  __syncthreads();

  float sm0 = 0.f, sm1 = 0.f;

  // ---- phase 1: H_hat = clip(QK^T)+E; no-max expsum ----
  #pragma unroll 2
  for (int k = 0; k < NTILE; k++){
    const float e0 = e2[k&1][0], e1 = e2[k&1][1];
    if (k+2 < NTILE){
      stage_issue(QKV, qkvbase, k+2, 256, srow, shs, sjp, sf[k&1]);
      e2[k&1][0] = E[ebase0 + (k+2)*256 + eoff];
      e2[k&1][1] = E[ebase1 + (k+2)*256 + eoff];
    }
    if (k+1 < NTILE) stage_write(kvb, (k+1)&1, srow, shs, sjp, sf[(k+1)&1]);

    float acc0 = 0.f, acc1 = 0.f;
    const h2* kr = &kvb[((k&1)*KT + mg2)*RS + h*HS];
    #pragma unroll
    for (int jw = 0; jw < 4; jw++){
      h8 kk = *(const h8*)&kr[jw*4];
      #pragma unroll
      for (int u = 0; u < 4; u++){
        h2 kj; kj[0] = kk[2*u]; kj[1] = kk[2*u+1];
        acc0 = dot2f(q0[jw*4+u], kj, acc0);
        acc1 = dot2f(q1[jw*4+u], kj, acc1);
      }
    }
    float h0 = fminf(fmaxf(acc0, -5.f), 5.f) + e0;
    float h1 = fminf(fmaxf(acc1, -5.f), 5.f) + e1;
    out[OFF_H + ebase0 + k*256 + eoff] = h0;
    out[OFF_H + ebase1 + k*256 + eoff] = h1;
    sm0 += __expf(h0);
    sm1 += __expf(h1);
    __syncthreads();
  }

  // ---- phase-2 V prefetch starts now, overlaps the sum reduction ----
  stage_issue(QKV, qkvbase, 0, 512, srow, shs, sjp, sf[0]);
  stage_issue(QKV, qkvbase, 1, 512, srow, shs, sjp, sf[1]);

  // ---- expsum reduce over m ----
  sm0 += __shfl_xor(sm0, 16); sm0 += __shfl_xor(sm0, 32);
  sm1 += __shfl_xor(sm1, 16); sm1 += __shfl_xor(sm1, 32);
  if (((t >> 4) & 3) == 0){ red[w][lh][h][0] = sm0; red[w][lh][h][1] = sm1; }
  __syncthreads();
  float tot0 = 0.f, tot1 = 0.f;
  #pragma unroll
  for (int ww = 0; ww < 8; ww++){ tot0 += red[ww][lh][h][0]; tot1 += red[ww][lh][h][1]; }
  const float rcp0 = 1.f / tot0, rcp1 = 1.f / tot1;

  // ---- phase-2 prologue: A(0) computed; G/H(1),(2) in flight ----
  float gh[2][4];
  float dg0, dg1;
  {
    float ga0 = G[ebase0 + eoff];
    float ga1 = G[ebase1 + eoff];
    float ha0 = out[OFF_H + ebase0 + eoff];
    float ha1 = out[OFF_H + ebase1 + eoff];
    gh[1][0] = G[ebase0 + 256 + eoff];
    gh[1][1] = G[ebase1 + 256 + eoff];
    gh[1][2] = out[OFF_H + ebase0 + 256 + eoff];
    gh[1][3] = out[OFF_H + ebase1 + 256 + eoff];
    gh[0][0] = G[ebase0 + 512 + eoff];
    gh[0][1] = G[ebase1 + 512 + eoff];
    gh[0][2] = out[OFF_H + ebase0 + 512 + eoff];
    gh[0][3] = out[OFF_H + ebase1 + 512 + eoff];
    float sig0 = 1.f / (1.f + __expf(-ga0));
    float sig1 = 1.f / (1.f + __expf(-ga1));
    float A0 = __expf(ha0) * rcp0 * sig0;
    float A1 = __expf(ha1) * rcp1 * sig1;
    dg0 = sig0; dg1 = sig1;
    out[OFF_A + ebase0 + eoff] = A0;
    out[OFF_A + ebase1 + eoff] = A1;
    ((h2*)&at2h[0][mg2][h])[lh] = __builtin_amdgcn_cvt_pkrtz(A0, A1);
    stage_write(kvb, 0, srow, shs, sjp, sf[0]);
  }
  __syncthreads();

  float vacc[4][4] = {{0.f,0.f,0.f,0.f},{0.f,0.f,0.f,0.f},{0.f,0.f,0.f,0.f},{0.f,0.f,0.f,0.f}};

  // ---- phase 2: A(k+1) pipelined ahead of PV(k) ----
  #pragma unroll 2
  for (int k = 0; k < NTILE; k++){
    if (k+2 < NTILE) stage_issue(QKV, qkvbase, k+2, 512, srow, shs, sjp, sf[k&1]);

    if (k+1 < NTILE){
      const int a = k+1;
      float ga0 = gh[a&1][0], ga1 = gh[a&1][1];
      float ha0 = gh[a&1][2], ha1 = gh[a&1][3];
      if (a+2 < NTILE){
        gh[a&1][0] = G[ebase0 + (a+2)*256 + eoff];
        gh[a&1][1] = G[ebase1 + (a+2)*256 + eoff];
        gh[a&1][2] = out[OFF_H + ebase0 + (a+2)*256 + eoff];
        gh[a&1][3] = out[OFF_H + ebase1 + (a+2)*256 + eoff];
      }
      float sig0 = 1.f / (1.f + __expf(-ga0));
      float sig1 = 1.f / (1.f + __expf(-ga1));
      float A0 = __expf(ha0) * rcp0 * sig0;
      float A1 = __expf(ha1) * rcp1 * sig1;
      dg0 += sig0; dg1 += sig1;
      out[OFF_A + ebase0 + a*256 + eoff] = A0;
      out[OFF_A + ebase1 + a*256 + eoff] = A1;
      ((h2*)&at2h[a&1][mg2][h])[lh] = __builtin_amdgcn_cvt_pkrtz(A0, A1);
      stage_write(kvb, a&1, srow, shs, sjp, sf[a&1]);
    }

    // PV from V slot k&1 and at2h[k&1]
    #pragma unroll
    for (int i = 0; i < 4; i++){
      const int mm = pmq + 8*i;
      h4 vv = *(const h4*)&kvb[((k&1)*KT + mm)*RS + ph*HS + 2*pdq];
      h4 aa = at2h[k&1][mm][ph];
      float vf0 = (float)vv[0], vf1 = (float)vv[1], vf2 = (float)vv[2], vf3 = (float)vv[3];
      float a0 = (float)aa[0], a1 = (float)aa[1], a2 = (float)aa[2], a3 = (float)aa[3];
      vacc[0][0] = fmaf(a0, vf0, vacc[0][0]); vacc[0][1] = fmaf(a0, vf1, vacc[0][1]);
      vacc[0][2] = fmaf(a0, vf2, vacc[0][2]); vacc[0][3] = fmaf(a0, vf3, vacc[0][3]);
      vacc[1][0] = fmaf(a1, vf0, vacc[1][0]); vacc[1][1] = fmaf(a1, vf1, vacc[1][1]);
      vacc[1][2] = fmaf(a1, vf2, vacc[1][2]); vacc[1][3] = fmaf(a1, vf3, vacc[1][3]);
      vacc[2][0] = fmaf(a2, vf0, vacc[2][0]); vacc[2][1] = fmaf(a2, vf1, vacc[2][1]);
      vacc[2][2] = fmaf(a2, vf2, vacc[2][2]); vacc[2][3] = fmaf(a2, vf3, vacc[2][3]);
      vacc[3][0] = fmaf(a3, vf0, vacc[3][0]); vacc[3][1] = fmaf(a3, vf1, vacc[3][1]);
      vacc[3][2] = fmaf(a3, vf2, vacc[3][2]); vacc[3][3] = fmaf(a3, vf3, vacc[3][3]);
    }
    __syncthreads();
  }

  // ---- degrees -> log1p scalers ----
  dg0 += __shfl_xor(dg0, 16); dg0 += __shfl_xor(dg0, 32);
  dg1 += __shfl_xor(dg1, 16); dg1 += __shfl_xor(dg1, 32);
  if (((t >> 4) & 3) == 0){ red[w][lh][h][0] = dg0; red[w][lh][h][1] = dg1; }
  __syncthreads();
  if (t < 16){
    float td0 = 0.f, td1 = 0.f;
    #pragma unroll
    for (int ww = 0; ww < 8; ww++){ td0 += red[ww][lh][h][0]; td1 += red[ww][lh][h][1]; }
    fin[2*lh + 0][h] = log1pf(td0);
    fin[2*lh + 1][h] = log1pf(td1);
  }
  __syncthreads();

  // ---- reduce PV over m-slices, write V_att ----
  #pragma unroll
  for (int l = 0; l < 4; l++){
    #pragma unroll
    for (int di = 0; di < 4; di++){
      float v = vacc[l][di];
      v += __shfl_xor(v, 1); v += __shfl_xor(v, 2); v += __shfl_xor(v, 4);
      vacc[l][di] = v;
    }
  }
  if (pmq == 0){
    float sc0 = fin[0][ph], sc1 = fin[1][ph], sc2 = fin[2][ph], sc3 = fin[3][ph];
    const int obase = (b*1024 + l0) * 256;
    #pragma unroll
    for (int di = 0; di < 4; di++){
      const int c = (pdq*4 + di)*8 + ph;
      out[obase +   0 + c] = vacc[0][di] * sc0;
      out[obase + 256 + c] = vacc[1][di] * sc1;
      out[obase + 512 + c] = vacc[2][di] * sc2;
      out[obase + 768 + c] = vacc[3][di] * sc3;
    }
  }
}

extern "C" void kernel_launch(void* const* d_in, const int* in_sizes, int n_in,
                              void* d_out, int out_size, void* d_ws, size_t ws_size,
                              hipStream_t stream) {
  const float* QKV = (const float*)d_in[0];
  const float* E   = (const float*)d_in[1];
  const float* G   = (const float*)d_in[2];
  float* out = (float*)d_out;
  dim3 grid(1024);
  egt_fused<<<grid, NT, 0, stream>>>(QKV, E, G, out);
}

// Round 10
// 537.646 us; speedup vs baseline: 1.8739x; 1.8739x over previous
//
#include <hip/hip_runtime.h>

#define NHEAD 8
#define NT 512
#define KT 32
#define NTILE 32
#define RS 166          // dwords per m-row in kv tile: 8 heads x 20 + 6 pad (R7-proven)
#define HS 20           // per-head stride in dwords (16 data + 4 pad, 16B-aligned)
#define OFF_H 1048576
#define OFF_A 34603008

typedef __fp16 h2 __attribute__((ext_vector_type(2)));
typedef __fp16 h4 __attribute__((ext_vector_type(4)));
typedef __fp16 h8 __attribute__((ext_vector_type(8)));

__device__ __forceinline__ float dot2f(h2 a, h2 b, float c){
#if __has_builtin(__builtin_amdgcn_fdot2)
  return __builtin_amdgcn_fdot2(a, b, c, false);
#else
  return fmaf((float)a[0], (float)b[0], fmaf((float)a[1], (float)b[1], c));
#endif
}

__device__ __forceinline__ void stage_issue(const float* __restrict__ QKV, size_t qkvbase,
                                            int tile, int off, int srow, int shs, int sjp,
                                            float4 sf[4]){
  const float* src = QKV + qkvbase + (size_t)(tile*KT + srow)*768 + off + sjp*32 + shs*4;
  #pragma unroll
  for (int dd = 0; dd < 4; dd++) sf[dd] = *(const float4*)(src + dd*8);
}

__device__ __forceinline__ void stage_write(h2* kvb, int slot, int srow, int shs, int sjp,
                                            const float4 sf[4]){
  #pragma unroll
  for (int hh = 0; hh < 4; hh++){
    h2 lo = __builtin_amdgcn_cvt_pkrtz(((const float*)&sf[0])[hh], ((const float*)&sf[1])[hh]);
    h2 hi = __builtin_amdgcn_cvt_pkrtz(((const float*)&sf[2])[hh], ((const float*)&sf[3])[hh]);
    h4 pk; pk[0]=lo[0]; pk[1]=lo[1]; pk[2]=hi[0]; pk[3]=hi[1];
    *(h4*)&kvb[(slot*KT + srow)*RS + (4*shs+hh)*HS + 2*sjp] = pk;
  }
}

__global__ __launch_bounds__(NT, 3) void egt_fused(
    const float* __restrict__ QKV, const float* __restrict__ E,
    const float* __restrict__ G, float* __restrict__ out)
{
  __shared__ __align__(16) h2 kvb[2*KT*RS];     // K/V ring, 2 slots (42.5 KB)
  __shared__ __align__(16) h4 at2h[2][KT][9];   // A fragments fp16, dbuf (4.6 KB)
  __shared__ float red[8][2][NHEAD][2];
  __shared__ float fin[4][NHEAD];

  const int t   = threadIdx.x;
  const int h   = t & 7;
  const int lh  = (t >> 3) & 1;
  const int mg2 = t >> 4;          // 0..31  (mapping-1: scores/E/G/A io)
  const int w   = t >> 6;
  const int srow = t >> 4;         // staging decode
  const int shs  = (t >> 3) & 1;
  const int sjp  = t & 7;
  const int pmq = t & 7;           // PV decode
  const int pdq = (t >> 3) & 7;
  const int ph  = t >> 6;
  const int b  = blockIdx.x >> 8;
  const int l0 = (blockIdx.x & 255) << 2;
  const size_t qkvbase = (size_t)(b * 1024) * 768;

  const int ebase0 = (b*1024 + l0 + 2*lh) * 8192;
  const int ebase1 = ebase0 + 8192;
  const int eoff = mg2*8 + h;

  // ---- pack Q into registers (fp16 pairs over d) ----
  h2 q0[16], q1[16];
  {
    const float* qp0 = QKV + qkvbase + (size_t)(l0 + 2*lh) * 768 + h;
    const float* qp1 = qp0 + 768;
    #pragma unroll
    for (int jd = 0; jd < 16; jd++){
      q0[jd] = __builtin_amdgcn_cvt_pkrtz(qp0[jd*16], qp0[jd*16 + 8]);
      q1[jd] = __builtin_amdgcn_cvt_pkrtz(qp1[jd*16], qp1[jd*16 + 8]);
    }
  }

  float4 sf[2][4];
  float  e2[2][2];

  // ---- phase-1 prologue: K(0),K(1) + E(0),E(1) in flight ----
  stage_issue(QKV, qkvbase, 0, 256, srow, shs, sjp, sf[0]);
  stage_issue(QKV, qkvbase, 1, 256, srow, shs, sjp, sf[1]);
  e2[0][0] = E[ebase0 + eoff];
  e2[0][1] = E[ebase1 + eoff];
  e2[1][0] = E[ebase0 + 256 + eoff];
  e2[1][1] = E[ebase1 + 256 + eoff];
  stage_write(kvb, 0, srow, shs, sjp, sf[0]);
  __syncthreads();

  float sm0 = 0.f, sm1 = 0.f;

  // ---- phase 1: H_hat = clip(QK^T)+E; no-max expsum ----
  #pragma unroll 2
  for (int k = 0; k < NTILE; k++){
    const float e0 = e2[k&1][0], e1 = e2[k&1][1];
    if (k+2 < NTILE){
      stage_issue(QKV, qkvbase, k+2, 256, srow, shs, sjp, sf[k&1]);
      e2[k&1][0] = E[ebase0 + (k+2)*256 + eoff];
      e2[k&1][1] = E[ebase1 + (k+2)*256 + eoff];
    }
    if (k+1 < NTILE) stage_write(kvb, (k+1)&1, srow, shs, sjp, sf[(k+1)&1]);

    float acc0 = 0.f, acc1 = 0.f;
    const h2* kr = &kvb[((k&1)*KT + mg2)*RS + h*HS];
    #pragma unroll
    for (int jw = 0; jw < 4; jw++){
      h8 kk = *(const h8*)&kr[jw*4];
      #pragma unroll
      for (int u = 0; u < 4; u++){
        h2 kj; kj[0] = kk[2*u]; kj[1] = kk[2*u+1];
        acc0 = dot2f(q0[jw*4+u], kj, acc0);
        acc1 = dot2f(q1[jw*4+u], kj, acc1);
      }
    }
    float h0 = fminf(fmaxf(acc0, -5.f), 5.f) + e0;
    float h1 = fminf(fmaxf(acc1, -5.f), 5.f) + e1;
    out[OFF_H + ebase0 + k*256 + eoff] = h0;
    out[OFF_H + ebase1 + k*256 + eoff] = h1;
    sm0 += __expf(h0);
    sm1 += __expf(h1);
    __syncthreads();
  }

  // ---- phase-2 V prefetch starts now, overlaps the sum reduction ----
  stage_issue(QKV, qkvbase, 0, 512, srow, shs, sjp, sf[0]);
  stage_issue(QKV, qkvbase, 1, 512, srow, shs, sjp, sf[1]);

  // ---- expsum reduce over m ----
  sm0 += __shfl_xor(sm0, 16); sm0 += __shfl_xor(sm0, 32);
  sm1 += __shfl_xor(sm1, 16); sm1 += __shfl_xor(sm1, 32);
  if (((t >> 4) & 3) == 0){ red[w][lh][h][0] = sm0; red[w][lh][h][1] = sm1; }
  __syncthreads();
  float tot0 = 0.f, tot1 = 0.f;
  #pragma unroll
  for (int ww = 0; ww < 8; ww++){ tot0 += red[ww][lh][h][0]; tot1 += red[ww][lh][h][1]; }
  const float rcp0 = 1.f / tot0, rcp1 = 1.f / tot1;

  // ---- phase-2 prologue: A(0) computed; G/H(1),(2) in flight ----
  float gh[2][4];
  float dg0, dg1;
  {
    float ga0 = G[ebase0 + eoff];
    float ga1 = G[ebase1 + eoff];
    float ha0 = out[OFF_H + ebase0 + eoff];
    float ha1 = out[OFF_H + ebase1 + eoff];
    gh[1][0] = G[ebase0 + 256 + eoff];
    gh[1][1] = G[ebase1 + 256 + eoff];
    gh[1][2] = out[OFF_H + ebase0 + 256 + eoff];
    gh[1][3] = out[OFF_H + ebase1 + 256 + eoff];
    gh[0][0] = G[ebase0 + 512 + eoff];
    gh[0][1] = G[ebase1 + 512 + eoff];
    gh[0][2] = out[OFF_H + ebase0 + 512 + eoff];
    gh[0][3] = out[OFF_H + ebase1 + 512 + eoff];
    float sig0 = 1.f / (1.f + __expf(-ga0));
    float sig1 = 1.f / (1.f + __expf(-ga1));
    float A0 = __expf(ha0) * rcp0 * sig0;
    float A1 = __expf(ha1) * rcp1 * sig1;
    dg0 = sig0; dg1 = sig1;
    out[OFF_A + ebase0 + eoff] = A0;
    out[OFF_A + ebase1 + eoff] = A1;
    ((h2*)&at2h[0][mg2][h])[lh] = __builtin_amdgcn_cvt_pkrtz(A0, A1);
    stage_write(kvb, 0, srow, shs, sjp, sf[0]);
  }
  __syncthreads();

  float vacc[4][4] = {{0.f,0.f,0.f,0.f},{0.f,0.f,0.f,0.f},{0.f,0.f,0.f,0.f},{0.f,0.f,0.f,0.f}};

  // ---- phase 2: A(k+1) pipelined ahead of PV(k) ----
  #pragma unroll 2
  for (int k = 0; k < NTILE; k++){
    if (k+2 < NTILE) stage_issue(QKV, qkvbase, k+2, 512, srow, shs, sjp, sf[k&1]);

    if (k+1 < NTILE){
      const int a = k+1;
      float ga0 = gh[a&1][0], ga1 = gh[a&1][1];
      float ha0 = gh[a&1][2], ha1 = gh[a&1][3];
      if (a+2 < NTILE){
        gh[a&1][0] = G[ebase0 + (a+2)*256 + eoff];
        gh[a&1][1] = G[ebase1 + (a+2)*256 + eoff];
        gh[a&1][2] = out[OFF_H + ebase0 + (a+2)*256 + eoff];
        gh[a&1][3] = out[OFF_H + ebase1 + (a+2)*256 + eoff];
      }
      float sig0 = 1.f / (1.f + __expf(-ga0));
      float sig1 = 1.f / (1.f + __expf(-ga1));
      float A0 = __expf(ha0) * rcp0 * sig0;
      float A1 = __expf(ha1) * rcp1 * sig1;
      dg0 += sig0; dg1 += sig1;
      out[OFF_A + ebase0 + a*256 + eoff] = A0;
      out[OFF_A + ebase1 + a*256 + eoff] = A1;
      ((h2*)&at2h[a&1][mg2][h])[lh] = __builtin_amdgcn_cvt_pkrtz(A0, A1);
      stage_write(kvb, a&1, srow, shs, sjp, sf[a&1]);
    }

    // PV from V slot k&1 and at2h[k&1]
    #pragma unroll
    for (int i = 0; i < 4; i++){
      const int mm = pmq + 8*i;
      h4 vv = *(const h4*)&kvb[((k&1)*KT + mm)*RS + ph*HS + 2*pdq];
      h4 aa = at2h[k&1][mm][ph];
      float vf0 = (float)vv[0], vf1 = (float)vv[1], vf2 = (float)vv[2], vf3 = (float)vv[3];
      float a0 = (float)aa[0], a1 = (float)aa[1], a2 = (float)aa[2], a3 = (float)aa[3];
      vacc[0][0] = fmaf(a0, vf0, vacc[0][0]); vacc[0][1] = fmaf(a0, vf1, vacc[0][1]);
      vacc[0][2] = fmaf(a0, vf2, vacc[0][2]); vacc[0][3] = fmaf(a0, vf3, vacc[0][3]);
      vacc[1][0] = fmaf(a1, vf0, vacc[1][0]); vacc[1][1] = fmaf(a1, vf1, vacc[1][1]);
      vacc[1][2] = fmaf(a1, vf2, vacc[1][2]); vacc[1][3] = fmaf(a1, vf3, vacc[1][3]);
      vacc[2][0] = fmaf(a2, vf0, vacc[2][0]); vacc[2][1] = fmaf(a2, vf1, vacc[2][1]);
      vacc[2][2] = fmaf(a2, vf2, vacc[2][2]); vacc[2][3] = fmaf(a2, vf3, vacc[2][3]);
      vacc[3][0] = fmaf(a3, vf0, vacc[3][0]); vacc[3][1] = fmaf(a3, vf1, vacc[3][1]);
      vacc[3][2] = fmaf(a3, vf2, vacc[3][2]); vacc[3][3] = fmaf(a3, vf3, vacc[3][3]);
    }
    __syncthreads();
  }

  // ---- degrees -> log1p scalers ----
  dg0 += __shfl_xor(dg0, 16); dg0 += __shfl_xor(dg0, 32);
  dg1 += __shfl_xor(dg1, 16); dg1 += __shfl_xor(dg1, 32);
  if (((t >> 4) & 3) == 0){ red[w][lh][h][0] = dg0; red[w][lh][h][1] = dg1; }
  __syncthreads();
  if (t < 16){
    float td0 = 0.f, td1 = 0.f;
    #pragma unroll
    for (int ww = 0; ww < 8; ww++){ td0 += red[ww][lh][h][0]; td1 += red[ww][lh][h][1]; }
    fin[2*lh + 0][h] = log1pf(td0);
    fin[2*lh + 1][h] = log1pf(td1);
  }
  __syncthreads();

  // ---- reduce PV over m-slices, write V_att ----
  #pragma unroll
  for (int l = 0; l < 4; l++){
    #pragma unroll
    for (int di = 0; di < 4; di++){
      float v = vacc[l][di];
      v += __shfl_xor(v, 1); v += __shfl_xor(v, 2); v += __shfl_xor(v, 4);
      vacc[l][di] = v;
    }
  }
  if (pmq == 0){
    float sc0 = fin[0][ph], sc1 = fin[1][ph], sc2 = fin[2][ph], sc3 = fin[3][ph];
    const int obase = (b*1024 + l0) * 256;
    #pragma unroll
    for (int di = 0; di < 4; di++){
      const int c = (pdq*4 + di)*8 + ph;
      out[obase +   0 + c] = vacc[0][di] * sc0;
      out[obase + 256 + c] = vacc[1][di] * sc1;
      out[obase + 512 + c] = vacc[2][di] * sc2;
      out[obase + 768 + c] = vacc[3][di] * sc3;
    }
  }
}

extern "C" void kernel_launch(void* const* d_in, const int* in_sizes, int n_in,
                              void* d_out, int out_size, void* d_ws, size_t ws_size,
                              hipStream_t stream) {
  const float* QKV = (const float*)d_in[0];
  const float* E   = (const float*)d_in[1];
  const float* G   = (const float*)d_in[2];
  float* out = (float*)d_out;
  dim3 grid(1024);
  egt_fused<<<grid, NT, 0, stream>>>(QKV, E, G, out);
}

// Round 11
// 341.867 us; speedup vs baseline: 2.9470x; 1.5727x over previous
//
#include <hip/hip_runtime.h>

#define NHEAD 8
#define NT 512
#define KT 32
#define NTILE 32
#define RS 166          // h2 (dword) stride per m-row in kv tile (8*20 + 6 pad)
#define HS 20
#define OFF_H 1048576
#define OFF_A 34603008

// Light barrier: orders LDS ops only; leaves global loads (vmcnt) in flight.
#define LBAR() asm volatile("s_waitcnt lgkmcnt(0)\n\ts_barrier" ::: "memory")

typedef __fp16 h2 __attribute__((ext_vector_type(2)));
typedef __fp16 h4 __attribute__((ext_vector_type(4)));
typedef __fp16 h8 __attribute__((ext_vector_type(8)));

__device__ __forceinline__ float dot2f(h2 a, h2 b, float c){
#if __has_builtin(__builtin_amdgcn_fdot2)
  return __builtin_amdgcn_fdot2(a, b, c, false);
#else
  return fmaf((float)a[0], (float)b[0], fmaf((float)a[1], (float)b[1], c));
#endif
}

__device__ __forceinline__ void stage_issue(const float* __restrict__ QKV, size_t qkvbase,
                                            int tile, int off, int srow, int shs, int sjp,
                                            float4 sf[4]){
  const float* src = QKV + qkvbase + (size_t)(tile*KT + srow)*768 + off + sjp*32 + shs*4;
  #pragma unroll
  for (int dd = 0; dd < 4; dd++) sf[dd] = *(const float4*)(src + dd*8);
}

__device__ __forceinline__ void stage_write(h2* kvb, int slot, int srow, int shs, int sjp,
                                            const float4 sf[4]){
  #pragma unroll
  for (int hh = 0; hh < 4; hh++){
    h2 lo = __builtin_amdgcn_cvt_pkrtz(((const float*)&sf[0])[hh], ((const float*)&sf[1])[hh]);
    h2 hi = __builtin_amdgcn_cvt_pkrtz(((const float*)&sf[2])[hh], ((const float*)&sf[3])[hh]);
    h4 pk; pk[0]=lo[0]; pk[1]=lo[1]; pk[2]=hi[0]; pk[3]=hi[1];
    *(h4*)&kvb[(slot*KT + srow)*RS + (4*shs+hh)*HS + 2*sjp] = pk;
  }
}

__global__ __launch_bounds__(NT, 4) void egt_fused(
    const float* __restrict__ QKV, const float* __restrict__ E,
    const float* __restrict__ G, float* __restrict__ out)
{
  __shared__ __align__(16) h2 kvb[2*KT*RS];        // K/V ring, 2 slots (42.5 KB)
  __shared__ __align__(16) float at2[2][KT][9][4]; // A fragments fp32, dbuf (9.2 KB)
  __shared__ float red[8][2][NHEAD][2];
  __shared__ float fin[4][NHEAD];

  const int t   = threadIdx.x;
  const int h   = t & 7;
  const int lh  = (t >> 3) & 1;
  const int mg2 = t >> 4;          // 0..31  (mapping-1: scores/E/G/A io)
  const int w   = t >> 6;
  const int srow = t >> 4;         // staging decode
  const int shs  = (t >> 3) & 1;
  const int sjp  = t & 7;
  const int pmq = t & 7;           // PV decode
  const int pdq = (t >> 3) & 7;
  const int ph  = t >> 6;
  const int b  = blockIdx.x >> 8;
  const int l0 = (blockIdx.x & 255) << 2;
  const size_t qkvbase = (size_t)(b * 1024) * 768;

  const int ebase0 = (b*1024 + l0 + 2*lh) * 8192;
  const int ebase1 = ebase0 + 8192;
  const int eoff = mg2*8 + h;

  // ---- pack Q into registers (fp16 pairs over d) ----
  h2 q0[16], q1[16];
  {
    const float* qp0 = QKV + qkvbase + (size_t)(l0 + 2*lh) * 768 + h;
    const float* qp1 = qp0 + 768;
    #pragma unroll
    for (int jd = 0; jd < 16; jd++){
      q0[jd] = __builtin_amdgcn_cvt_pkrtz(qp0[jd*16], qp0[jd*16 + 8]);
      q1[jd] = __builtin_amdgcn_cvt_pkrtz(qp1[jd*16], qp1[jd*16 + 8]);
    }
  }

  float4 sf[2][4];
  float  e2[2][2];

  // ---- phase-1 prologue: K(0),K(1) + E(0),E(1) in flight ----
  stage_issue(QKV, qkvbase, 0, 256, srow, shs, sjp, sf[0]);
  stage_issue(QKV, qkvbase, 1, 256, srow, shs, sjp, sf[1]);
  e2[0][0] = E[ebase0 + eoff];
  e2[0][1] = E[ebase1 + eoff];
  e2[1][0] = E[ebase0 + 256 + eoff];
  e2[1][1] = E[ebase1 + 256 + eoff];
  stage_write(kvb, 0, srow, shs, sjp, sf[0]);
  __syncthreads();

  float sm0 = 0.f, sm1 = 0.f;

  // ---- phase 1: H_hat = clip(QK^T)+E; no-max expsum; light barriers ----
  #pragma unroll 2
  for (int k = 0; k < NTILE; k++){
    const float e0 = e2[k&1][0], e1 = e2[k&1][1];
    if (k+2 < NTILE){
      stage_issue(QKV, qkvbase, k+2, 256, srow, shs, sjp, sf[k&1]);
      e2[k&1][0] = E[ebase0 + (k+2)*256 + eoff];
      e2[k&1][1] = E[ebase1 + (k+2)*256 + eoff];
    }
    if (k+1 < NTILE) stage_write(kvb, (k+1)&1, srow, shs, sjp, sf[(k+1)&1]);

    float acc0 = 0.f, acc1 = 0.f;
    const h2* kr = &kvb[((k&1)*KT + mg2)*RS + h*HS];
    #pragma unroll
    for (int jw = 0; jw < 4; jw++){
      h8 kk = *(const h8*)&kr[jw*4];
      #pragma unroll
      for (int u = 0; u < 4; u++){
        h2 kj; kj[0] = kk[2*u]; kj[1] = kk[2*u+1];
        acc0 = dot2f(q0[jw*4+u], kj, acc0);
        acc1 = dot2f(q1[jw*4+u], kj, acc1);
      }
    }
    float h0 = fminf(fmaxf(acc0, -5.f), 5.f) + e0;
    float h1 = fminf(fmaxf(acc1, -5.f), 5.f) + e1;
    out[OFF_H + ebase0 + k*256 + eoff] = h0;
    out[OFF_H + ebase1 + k*256 + eoff] = h1;
    sm0 += __expf(h0);
    sm1 += __expf(h1);
    LBAR();
  }

  // ---- phase-2 V prefetch starts now, overlaps the sum reduction ----
  stage_issue(QKV, qkvbase, 0, 512, srow, shs, sjp, sf[0]);
  stage_issue(QKV, qkvbase, 1, 512, srow, shs, sjp, sf[1]);

  // ---- expsum reduce over m ----
  sm0 += __shfl_xor(sm0, 16); sm0 += __shfl_xor(sm0, 32);
  sm1 += __shfl_xor(sm1, 16); sm1 += __shfl_xor(sm1, 32);
  if (((t >> 4) & 3) == 0){ red[w][lh][h][0] = sm0; red[w][lh][h][1] = sm1; }
  __syncthreads();
  float tot0 = 0.f, tot1 = 0.f;
  #pragma unroll
  for (int ww = 0; ww < 8; ww++){ tot0 += red[ww][lh][h][0]; tot1 += red[ww][lh][h][1]; }
  const float rcp0 = 1.f / tot0, rcp1 = 1.f / tot1;

  // ---- phase-2 prologue: A(0) computed; G/H(1),(2) in flight ----
  float gh[2][4];
  float dg0, dg1;
  {
    float ga0 = G[ebase0 + eoff];
    float ga1 = G[ebase1 + eoff];
    float ha0 = out[OFF_H + ebase0 + eoff];
    float ha1 = out[OFF_H + ebase1 + eoff];
    gh[1][0] = G[ebase0 + 256 + eoff];
    gh[1][1] = G[ebase1 + 256 + eoff];
    gh[1][2] = out[OFF_H + ebase0 + 256 + eoff];
    gh[1][3] = out[OFF_H + ebase1 + 256 + eoff];
    gh[0][0] = G[ebase0 + 512 + eoff];
    gh[0][1] = G[ebase1 + 512 + eoff];
    gh[0][2] = out[OFF_H + ebase0 + 512 + eoff];
    gh[0][3] = out[OFF_H + ebase1 + 512 + eoff];
    float sig0 = 1.f / (1.f + __expf(-ga0));
    float sig1 = 1.f / (1.f + __expf(-ga1));
    float A0 = __expf(ha0) * rcp0 * sig0;
    float A1 = __expf(ha1) * rcp1 * sig1;
    dg0 = sig0; dg1 = sig1;
    out[OFF_A + ebase0 + eoff] = A0;
    out[OFF_A + ebase1 + eoff] = A1;
    *(float2*)&at2[0][mg2][h][2*lh] = make_float2(A0, A1);
    stage_write(kvb, 0, srow, shs, sjp, sf[0]);
  }
  __syncthreads();

  float vacc[4][4] = {{0.f,0.f,0.f,0.f},{0.f,0.f,0.f,0.f},{0.f,0.f,0.f,0.f},{0.f,0.f,0.f,0.f}};

  // ---- phase 2: A(k+1) pipelined ahead of PV(k); light barriers ----
  #pragma unroll 2
  for (int k = 0; k < NTILE; k++){
    if (k+2 < NTILE) stage_issue(QKV, qkvbase, k+2, 512, srow, shs, sjp, sf[k&1]);

    if (k+1 < NTILE){
      const int a = k+1;
      float ga0 = gh[a&1][0], ga1 = gh[a&1][1];
      float ha0 = gh[a&1][2], ha1 = gh[a&1][3];
      if (a+2 < NTILE){
        gh[a&1][0] = G[ebase0 + (a+2)*256 + eoff];
        gh[a&1][1] = G[ebase1 + (a+2)*256 + eoff];
        gh[a&1][2] = out[OFF_H + ebase0 + (a+2)*256 + eoff];
        gh[a&1][3] = out[OFF_H + ebase1 + (a+2)*256 + eoff];
      }
      float sig0 = 1.f / (1.f + __expf(-ga0));
      float sig1 = 1.f / (1.f + __expf(-ga1));
      float A0 = __expf(ha0) * rcp0 * sig0;
      float A1 = __expf(ha1) * rcp1 * sig1;
      dg0 += sig0; dg1 += sig1;
      out[OFF_A + ebase0 + a*256 + eoff] = A0;
      out[OFF_A + ebase1 + a*256 + eoff] = A1;
      *(float2*)&at2[a&1][mg2][h][2*lh] = make_float2(A0, A1);
      stage_write(kvb, a&1, srow, shs, sjp, sf[a&1]);
    }

    // PV from V slot k&1 and at2[k&1]
    #pragma unroll
    for (int i = 0; i < 4; i++){
      const int mm = pmq + 8*i;
      h4 vv = *(const h4*)&kvb[((k&1)*KT + mm)*RS + ph*HS + 2*pdq];
      float4 aa = *(const float4*)&at2[k&1][mm][ph][0];
      float vf0 = (float)vv[0], vf1 = (float)vv[1], vf2 = (float)vv[2], vf3 = (float)vv[3];
      vacc[0][0] = fmaf(aa.x, vf0, vacc[0][0]); vacc[0][1] = fmaf(aa.x, vf1, vacc[0][1]);
      vacc[0][2] = fmaf(aa.x, vf2, vacc[0][2]); vacc[0][3] = fmaf(aa.x, vf3, vacc[0][3]);
      vacc[1][0] = fmaf(aa.y, vf0, vacc[1][0]); vacc[1][1] = fmaf(aa.y, vf1, vacc[1][1]);
      vacc[1][2] = fmaf(aa.y, vf2, vacc[1][2]); vacc[1][3] = fmaf(aa.y, vf3, vacc[1][3]);
      vacc[2][0] = fmaf(aa.z, vf0, vacc[2][0]); vacc[2][1] = fmaf(aa.z, vf1, vacc[2][1]);
      vacc[2][2] = fmaf(aa.z, vf2, vacc[2][2]); vacc[2][3] = fmaf(aa.z, vf3, vacc[2][3]);
      vacc[3][0] = fmaf(aa.w, vf0, vacc[3][0]); vacc[3][1] = fmaf(aa.w, vf1, vacc[3][1]);
      vacc[3][2] = fmaf(aa.w, vf2, vacc[3][2]); vacc[3][3] = fmaf(aa.w, vf3, vacc[3][3]);
    }
    LBAR();
  }

  // ---- degrees -> log1p scalers ----
  dg0 += __shfl_xor(dg0, 16); dg0 += __shfl_xor(dg0, 32);
  dg1 += __shfl_xor(dg1, 16); dg1 += __shfl_xor(dg1, 32);
  if (((t >> 4) & 3) == 0){ red[w][lh][h][0] = dg0; red[w][lh][h][1] = dg1; }
  __syncthreads();
  if (t < 16){
    float td0 = 0.f, td1 = 0.f;
    #pragma unroll
    for (int ww = 0; ww < 8; ww++){ td0 += red[ww][lh][h][0]; td1 += red[ww][lh][h][1]; }
    fin[2*lh + 0][h] = log1pf(td0);
    fin[2*lh + 1][h] = log1pf(td1);
  }
  __syncthreads();

  // ---- reduce PV over m-slices, write V_att ----
  #pragma unroll
  for (int l = 0; l < 4; l++){
    #pragma unroll
    for (int di = 0; di < 4; di++){
      float v = vacc[l][di];
      v += __shfl_xor(v, 1); v += __shfl_xor(v, 2); v += __shfl_xor(v, 4);
      vacc[l][di] = v;
    }
  }
  if (pmq == 0){
    float sc0 = fin[0][ph], sc1 = fin[1][ph], sc2 = fin[2][ph], sc3 = fin[3][ph];
    const int obase = (b*1024 + l0) * 256;
    #pragma unroll
    for (int di = 0; di < 4; di++){
      const int c = (pdq*4 + di)*8 + ph;
      out[obase +   0 + c] = vacc[0][di] * sc0;
      out[obase + 256 + c] = vacc[1][di] * sc1;
      out[obase + 512 + c] = vacc[2][di] * sc2;
      out[obase + 768 + c] = vacc[3][di] * sc3;
    }
  }
}

extern "C" void kernel_launch(void* const* d_in, const int* in_sizes, int n_in,
                              void* d_out, int out_size, void* d_ws, size_t ws_size,
                              hipStream_t stream) {
  const float* QKV = (const float*)d_in[0];
  const float* E   = (const float*)d_in[1];
  const float* G   = (const float*)d_in[2];
  float* out = (float*)d_out;
  dim3 grid(1024);
  egt_fused<<<grid, NT, 0, stream>>>(QKV, E, G, out);
}